// Round 2
// baseline (2979.801 us; speedup 1.0000x reference)
//
#include <hip/hip_runtime.h>
#include <hip/hip_bf16.h>

#define B_ 256
#define T_ 4096
#define I_ 64
#define H_ 36
#define G_ 144   // 4*H
#define O_ 2

typedef float v2f __attribute__((ext_vector_type(2)));

__device__ __forceinline__ float fsigmoid(float x) {
  // 1/(1+exp(-x)) = 1/(1+2^(-x*log2e))
  float e = __builtin_amdgcn_exp2f(x * -1.442695040888963f);
  return __builtin_amdgcn_rcpf(1.0f + e);
}
__device__ __forceinline__ float ftanh(float x) {
  // tanh(x) = 1 - 2/(1+2^(2x*log2e))
  float e = __builtin_amdgcn_exp2f(x * 2.885390081777926f);
  return 1.0f - 2.0f * __builtin_amdgcn_rcpf(1.0f + e);
}

// ---------------- xg = x @ W_ih^T + (b_ih + b_hh) ----------------
// rows = nT*B (one block = 64 rows x 144 cols)
__global__ __launch_bounds__(256) void xg_gemm(
    const float* __restrict__ x,      // [rows][64]
    const float* __restrict__ W_ih,   // [144][64]
    const float* __restrict__ b_ih,
    const float* __restrict__ b_hh,
    float* __restrict__ xg)           // [rows][144]
{
  __shared__ float Wt[64 * 145];      // Wt[k][g], row stride 145 (pad: bank spread)
  __shared__ float xt[64 * 68];       // xt[k][r], row stride 68 (16B-aligned rows)
  __shared__ float bias[G_];

  const int tid = threadIdx.x;
  for (int idx = tid; idx < G_ * I_; idx += 256) {
    int g = idx >> 6, k = idx & 63;
    Wt[k * 145 + g] = W_ih[idx];
  }
  if (tid < G_) bias[tid] = b_ih[tid] + b_hh[tid];

  const long r0 = (long)blockIdx.x * 64;
  const float4* xin = (const float4*)(x + r0 * I_);
#pragma unroll
  for (int v = 0; v < 4; v++) {
    int idx = tid + v * 256;          // float4 index within 64x64 tile
    float4 d = xin[idx];
    int r = idx >> 4;                 // 16 float4 per row
    int kk = (idx & 15) << 2;
    xt[(kk + 0) * 68 + r] = d.x;
    xt[(kk + 1) * 68 + r] = d.y;
    xt[(kk + 2) * 68 + r] = d.z;
    xt[(kk + 3) * 68 + r] = d.w;
  }
  __syncthreads();

  const int tr = tid >> 4;            // 0..15 -> 4 rows each
  const int tc = tid & 15;            // 0..15 -> 9 cols each
  float acc[4][9];
#pragma unroll
  for (int rr = 0; rr < 4; rr++)
#pragma unroll
    for (int c = 0; c < 9; c++) acc[rr][c] = 0.0f;

#pragma unroll 4
  for (int k = 0; k < 64; k++) {
    float4 xv = *(const float4*)&xt[k * 68 + (tr << 2)];
    const float* wr = &Wt[k * 145 + tc * 9];
#pragma unroll
    for (int c = 0; c < 9; c++) {
      float w = wr[c];
      acc[0][c] = fmaf(xv.x, w, acc[0][c]);
      acc[1][c] = fmaf(xv.y, w, acc[1][c]);
      acc[2][c] = fmaf(xv.z, w, acc[2][c]);
      acc[3][c] = fmaf(xv.w, w, acc[3][c]);
    }
  }

#pragma unroll
  for (int rr = 0; rr < 4; rr++) {
    long r = r0 + (tr << 2) + rr;
    float* out = xg + r * G_ + tc * 9;
#pragma unroll
    for (int c = 0; c < 9; c++) out[c] = acc[rr][c] + bias[tc * 9 + c];
  }
}

// ---------------- sequential LSTM scan, 1 wave per batch element ----------------
// lane j<36: owns h[j], c[j]; computes gates i,f,g,o for index j.
// lanes 36/37: compute y[t-1][b][0/1] (pipelined one step behind).
__global__ __launch_bounds__(64, 1) void lstm_scan(
    const float* __restrict__ xg,     // [nT][B][144] (chunk-local)
    const float* __restrict__ W_hh,   // [144][36]
    const float* __restrict__ W_out,  // [2][36]
    const float* __restrict__ b_out,  // [2]
    float* __restrict__ y,            // [T][B][2] (global, fp32)
    float* __restrict__ hc,           // [2][B][36] carry state
    int t0, int nT)
{
  const int b = blockIdx.x;
  const int j = threadIdx.x;

  v2f wif[H_], wgo[H_];
  if (j < H_) {
#pragma unroll
    for (int k = 0; k < H_; k++) {
      wif[k].x = W_hh[(j) * H_ + k];
      wif[k].y = W_hh[(j + H_) * H_ + k];
      wgo[k].x = W_hh[(j + 2 * H_) * H_ + k];
      wgo[k].y = W_hh[(j + 3 * H_) * H_ + k];
    }
  } else if (j < H_ + O_) {
    const int o = j - H_;
#pragma unroll
    for (int k = 0; k < H_; k++) {
      wif[k].x = W_out[o * H_ + k];
      wif[k].y = 0.0f;
      wgo[k].x = 0.0f;
      wgo[k].y = 0.0f;
    }
  } else {
#pragma unroll
    for (int k = 0; k < H_; k++) {
      wif[k].x = 0.0f; wif[k].y = 0.0f;
      wgo[k].x = 0.0f; wgo[k].y = 0.0f;
    }
  }

  float hj = 0.0f, cj = 0.0f;
  if (t0 > 0 && j < H_) {
    hj = hc[b * H_ + j];
    cj = hc[B_ * H_ + b * H_ + j];
  }
  const float yb = (j == H_ || j == H_ + 1) ? b_out[j - H_] : 0.0f;

  const float* xgb = xg + (size_t)b * G_;
  const int jj = (j < H_) ? j : 0;

  auto LD = [&](int t, float* dst) {
    const float* p = xgb + (size_t)t * (B_ * G_);
    dst[0] = p[jj];
    dst[1] = p[jj + H_];
    dst[2] = p[jj + 2 * H_];
    dst[3] = p[jj + 3 * H_];
  };

  float p0[4], p1[4];
  LD(0, p0);
  LD(nT > 1 ? 1 : 0, p1);

#pragma unroll 2
  for (int t = 0; t < nT; t++) {
    float pf[4];
    {
      int tn = (t + 2 < nT) ? (t + 2) : (nT - 1);
      LD(tn, pf);
    }

    v2f aif, ago;
    if (j < H_) {
      aif.x = p0[0]; aif.y = p0[1];
      ago.x = p0[2]; ago.y = p0[3];
    } else {
      aif.x = yb; aif.y = 0.0f;
      ago.x = 0.0f; ago.y = 0.0f;
    }

#pragma unroll
    for (int k = 0; k < H_; k++) {
      float hk = __int_as_float(__builtin_amdgcn_readlane(__float_as_int(hj), k));
      aif += wif[k] * hk;
      ago += wgo[k] * hk;
    }

    if (j < H_) {
      float ig = fsigmoid(aif.x);
      float fg = fsigmoid(aif.y);
      float gg = ftanh(ago.x);
      float og = fsigmoid(ago.y);
      cj = fg * cj + ig * gg;
      hj = og * ftanh(cj);
    } else if (j < H_ + O_) {
      int gt = t0 + t - 1;
      if (gt >= 0) y[((size_t)gt * B_ + b) * O_ + (j - H_)] = aif.x;
    }

    p0[0] = p1[0]; p0[1] = p1[1]; p0[2] = p1[2]; p0[3] = p1[3];
    p1[0] = pf[0]; p1[1] = pf[1]; p1[2] = pf[2]; p1[3] = pf[3];
  }

  // epilogue: y for the last step of this chunk
  {
    float a = yb;
#pragma unroll
    for (int k = 0; k < H_; k++) {
      float hk = __int_as_float(__builtin_amdgcn_readlane(__float_as_int(hj), k));
      a = fmaf(hk, wif[k].x, a);
    }
    if (j == H_ || j == H_ + 1) {
      int gt = t0 + nT - 1;
      y[((size_t)gt * B_ + b) * O_ + (j - H_)] = a;
    }
  }

  if (j < H_) {
    hc[b * H_ + j] = hj;
    hc[B_ * H_ + b * H_ + j] = cj;
  }
}

extern "C" void kernel_launch(void* const* d_in, const int* in_sizes, int n_in,
                              void* d_out, int out_size, void* d_ws, size_t ws_size,
                              hipStream_t stream) {
  const float* x     = (const float*)d_in[0];
  const float* W_ih  = (const float*)d_in[1];
  const float* W_hh  = (const float*)d_in[2];
  const float* b_ih  = (const float*)d_in[3];
  const float* b_hh  = (const float*)d_in[4];
  const float* W_out = (const float*)d_in[5];
  const float* b_out = (const float*)d_in[6];
  float* y           = (float*)d_out;

  const size_t stateBytes = 2ull * B_ * H_ * sizeof(float);
  int nT = T_;
  while (nT > 1 &&
         (size_t)nT * B_ * G_ * sizeof(float) + stateBytes > ws_size) {
    nT >>= 1;
  }

  float* xgbuf = (float*)d_ws;
  float* hc = (float*)((char*)d_ws + (size_t)nT * B_ * G_ * sizeof(float));

  for (int t0 = 0; t0 < T_; t0 += nT) {
    xg_gemm<<<dim3((nT * B_) / 64), dim3(256), 0, stream>>>(
        x + (size_t)t0 * B_ * I_, W_ih, b_ih, b_hh, xgbuf);
    lstm_scan<<<dim3(B_), dim3(64), 0, stream>>>(
        xgbuf, W_hh, W_out, b_out, y, hc, t0, nT);
  }
}

// Round 4
// 1780.193 us; speedup vs baseline: 1.6739x; 1.6739x over previous
//
#include <hip/hip_runtime.h>
#include <hip/hip_bf16.h>
#include <hip/hip_fp16.h>

#define B_ 256
#define T_ 4096
#define I_ 64
#define H_ 36
#define G_ 144   // 4*H
#define O_ 2
#define TS 32    // timesteps per LDS tile

typedef __fp16 h2 __attribute__((ext_vector_type(2)));

__device__ __forceinline__ float fsigmoid(float x) {
  float e = __builtin_amdgcn_exp2f(x * -1.442695040888963f);
  return __builtin_amdgcn_rcpf(1.0f + e);
}
__device__ __forceinline__ float ftanh(float x) {
  float e = __builtin_amdgcn_exp2f(x * 2.885390081777926f);
  return 1.0f - 2.0f * __builtin_amdgcn_rcpf(1.0f + e);
}
__device__ __forceinline__ h2 pack2(float lo, float hi) {
#if __has_builtin(__builtin_amdgcn_cvt_pkrtz)
  return __builtin_amdgcn_cvt_pkrtz(lo, hi);
#else
  h2 r; r.x = (__fp16)lo; r.y = (__fp16)hi; return r;
#endif
}
__device__ __forceinline__ float fdot2(h2 a, h2 b, float c) {
#if __has_builtin(__builtin_amdgcn_fdot2)
  return __builtin_amdgcn_fdot2(a, b, c, false);
#else
  return c + (float)a.x * (float)b.x + (float)a.y * (float)b.y;
#endif
}

// ---------------- xg = x @ W_ih^T + (b_ih+b_hh), stored [tile][B][TS][36][4] ----------------
__global__ __launch_bounds__(256) void xg_gemm(
    const float* __restrict__ x,      // [nT][B][64] (chunk-local)
    const float* __restrict__ W_ih,   // [144][64]
    const float* __restrict__ b_ih,
    const float* __restrict__ b_hh,
    float* __restrict__ xg)           // [nT/TS][B][TS][144] permuted (j*4+g)
{
  __shared__ float Wt[64 * 145];
  __shared__ float xt[64 * 68];
  __shared__ float bias[G_];

  const int tid = threadIdx.x;
  for (int idx = tid; idx < G_ * I_; idx += 256) {
    int g = idx >> 6, k = idx & 63;
    Wt[k * 145 + g] = W_ih[idx];
  }
  if (tid < G_) bias[tid] = b_ih[tid] + b_hh[tid];

  const long r0 = (long)blockIdx.x * 64;
  const float4* xin = (const float4*)(x + r0 * I_);
#pragma unroll
  for (int v = 0; v < 4; v++) {
    int idx = tid + v * 256;
    float4 d = xin[idx];
    int r = idx >> 4;
    int kk = (idx & 15) << 2;
    xt[(kk + 0) * 68 + r] = d.x;
    xt[(kk + 1) * 68 + r] = d.y;
    xt[(kk + 2) * 68 + r] = d.z;
    xt[(kk + 3) * 68 + r] = d.w;
  }
  __syncthreads();

  const int tr = tid >> 4;
  const int tc = tid & 15;
  float acc[4][9];
#pragma unroll
  for (int rr = 0; rr < 4; rr++)
#pragma unroll
    for (int c = 0; c < 9; c++) acc[rr][c] = 0.0f;

#pragma unroll 4
  for (int k = 0; k < 64; k++) {
    float4 xv = *(const float4*)&xt[k * 68 + (tr << 2)];
    const float* wr = &Wt[k * 145 + tc * 9];
#pragma unroll
    for (int c = 0; c < 9; c++) {
      float w = wr[c];
      acc[0][c] = fmaf(xv.x, w, acc[0][c]);
      acc[1][c] = fmaf(xv.y, w, acc[1][c]);
      acc[2][c] = fmaf(xv.z, w, acc[2][c]);
      acc[3][c] = fmaf(xv.w, w, acc[3][c]);
    }
  }

#pragma unroll
  for (int rr = 0; rr < 4; rr++) {
    long r = r0 + (tr << 2) + rr;          // r = t_local*B + b
    int t = (int)(r >> 8);                 // B_ = 256
    int b = (int)(r & 255);
    float* out = xg + (((size_t)(t >> 5) * B_ + b) * TS + (t & 31)) * G_;
#pragma unroll
    for (int cc = 0; cc < 9; cc++) {
      int c = tc * 9 + cc;
      int gate = c / 36, j = c - gate * 36;
      out[j * 4 + gate] = acc[rr][cc] + bias[c];
    }
  }
}

// ---------------- LSTM scan: wave0 = compute, wave1 = LDS prefetch ----------------
__global__ __launch_bounds__(128, 1) void lstm_scan(
    const float* __restrict__ xgT,    // [nT/TS][B][TS][36][4] (chunk-local)
    const float* __restrict__ W_hh,   // [144][36]
    const float* __restrict__ W_out,  // [2][36]
    const float* __restrict__ b_out,  // [2]
    float* __restrict__ y,            // [T][B][2] fp32
    float* __restrict__ hc,           // [2][B][36]
    int t0, int nT)
{
  __shared__ float4 buf[2][TS * 36];  // 36 KiB
  const int b = blockIdx.x;
  const int tid = threadIdx.x;
  const int j = tid & 63;
  const int ntiles = nT / TS;

  // ---- consumer state (only meaningful for wave 0) ----
  h2 wpi[18], wpf[18], wpg[18], wpo[18];
  float hj = 0.0f, cj = 0.0f, yb = 0.0f;
  int jj = 0;

  if (tid < 64) {
    if (j < H_) {
#pragma unroll
      for (int t = 0; t < 18; t++) {
        wpi[t] = pack2(W_hh[j * H_ + 2 * t],             W_hh[j * H_ + 2 * t + 1]);
        wpf[t] = pack2(W_hh[(j + H_) * H_ + 2 * t],      W_hh[(j + H_) * H_ + 2 * t + 1]);
        wpg[t] = pack2(W_hh[(j + 2 * H_) * H_ + 2 * t],  W_hh[(j + 2 * H_) * H_ + 2 * t + 1]);
        wpo[t] = pack2(W_hh[(j + 3 * H_) * H_ + 2 * t],  W_hh[(j + 3 * H_) * H_ + 2 * t + 1]);
      }
    } else if (j < H_ + O_) {
      const int o = j - H_;
#pragma unroll
      for (int t = 0; t < 18; t++) {
        wpi[t] = pack2(W_out[o * H_ + 2 * t], W_out[o * H_ + 2 * t + 1]);
        wpf[t] = pack2(0.f, 0.f); wpg[t] = pack2(0.f, 0.f); wpo[t] = pack2(0.f, 0.f);
      }
      yb = b_out[o];
    } else {
#pragma unroll
      for (int t = 0; t < 18; t++) {
        wpi[t] = pack2(0.f, 0.f); wpf[t] = pack2(0.f, 0.f);
        wpg[t] = pack2(0.f, 0.f); wpo[t] = pack2(0.f, 0.f);
      }
    }
    if (t0 > 0 && j < H_) {
      hj = hc[b * H_ + j];
      cj = hc[B_ * H_ + b * H_ + j];
    }
    jj = (j < H_) ? j : 0;
  }

  // ---- prologue: stage tile 0 ----
  if (tid >= 64) {
    const int pl = tid - 64;
    const float4* src = (const float4*)(xgT) + (size_t)b * (TS * 36);
#pragma unroll
    for (int q = 0; q < 18; q++) buf[0][q * 64 + pl] = src[q * 64 + pl];
  }
  __syncthreads();

  for (int tile = 0; tile < ntiles; ++tile) {
    if (tid >= 64) {
      if (tile + 1 < ntiles) {
        const int pl = tid - 64;
        const float4* src = (const float4*)(xgT) + ((size_t)(tile + 1) * B_ + b) * (TS * 36);
        float4* dst = &buf[(tile + 1) & 1][0];
        float4 tmp[18];
#pragma unroll
        for (int q = 0; q < 18; q++) tmp[q] = src[q * 64 + pl];
#pragma unroll
        for (int q = 0; q < 18; q++) dst[q * 64 + pl] = tmp[q];
      }
    } else {
      const float4* bp = &buf[tile & 1][0];
      float4 pc = bp[jj];
#pragma unroll 2
      for (int s = 0; s < TS; ++s) {
        float4 pn = bp[((s + 1) & (TS - 1)) * 36 + jj];  // prefetch next step

        float a_i, a_f, a_g, a_o;
        if (j < H_) { a_i = pc.x; a_f = pc.y; a_g = pc.z; a_o = pc.w; }
        else        { a_i = yb;   a_f = 0.f;  a_g = 0.f;  a_o = 0.f; }

        // pack h into half2 pairs, broadcast 18 of them
        float hn = __shfl_xor(hj, 1);
        float lo = (j & 1) ? hn : hj;
        float hi = (j & 1) ? hj : hn;
        int hpi = __builtin_bit_cast(int, pack2(lo, hi));
#pragma unroll
        for (int t = 0; t < 18; ++t) {
          int hb = __builtin_amdgcn_readlane(hpi, 2 * t);
          h2 hh = __builtin_bit_cast(h2, hb);
          a_i = fdot2(wpi[t], hh, a_i);
          a_f = fdot2(wpf[t], hh, a_f);
          a_g = fdot2(wpg[t], hh, a_g);
          a_o = fdot2(wpo[t], hh, a_o);
        }

        if (j < H_) {
          float ig = fsigmoid(a_i);
          float fg = fsigmoid(a_f);
          float gg = ftanh(a_g);
          float og = fsigmoid(a_o);
          cj = fg * cj + ig * gg;
          hj = og * ftanh(cj);
        } else if (j < H_ + O_) {
          int gt = t0 + tile * TS + s - 1;
          if (gt >= 0) y[((size_t)gt * B_ + b) * O_ + (j - H_)] = a_i;
        }
        pc = pn;
      }
    }
    __syncthreads();
  }

  // ---- epilogue: last y of chunk + state carry ----
  if (tid < 64) {
    float hn = __shfl_xor(hj, 1);
    float lo = (j & 1) ? hn : hj;
    float hi = (j & 1) ? hj : hn;
    int hpi = __builtin_bit_cast(int, pack2(lo, hi));
    float a = yb;
#pragma unroll
    for (int t = 0; t < 18; ++t) {
      int hb = __builtin_amdgcn_readlane(hpi, 2 * t);
      h2 hh = __builtin_bit_cast(h2, hb);
      a = fdot2(wpi[t], hh, a);
    }
    if (j == H_ || j == H_ + 1) {
      y[((size_t)(t0 + nT - 1) * B_ + b) * O_ + (j - H_)] = a;
    }
    if (j < H_) {
      hc[b * H_ + j] = hj;
      hc[B_ * H_ + b * H_ + j] = cj;
    }
  }
}

extern "C" void kernel_launch(void* const* d_in, const int* in_sizes, int n_in,
                              void* d_out, int out_size, void* d_ws, size_t ws_size,
                              hipStream_t stream) {
  const float* x     = (const float*)d_in[0];
  const float* W_ih  = (const float*)d_in[1];
  const float* W_hh  = (const float*)d_in[2];
  const float* b_ih  = (const float*)d_in[3];
  const float* b_hh  = (const float*)d_in[4];
  const float* W_out = (const float*)d_in[5];
  const float* b_out = (const float*)d_in[6];
  float* y           = (float*)d_out;

  const size_t stateBytes = 2ull * B_ * H_ * sizeof(float);
  int nT = T_;
  while (nT > TS &&
         (size_t)nT * B_ * G_ * sizeof(float) + stateBytes > ws_size) {
    nT >>= 1;
  }

  float* xgbuf = (float*)d_ws;
  float* hc = (float*)((char*)d_ws + (size_t)nT * B_ * G_ * sizeof(float));

  for (int t0 = 0; t0 < T_; t0 += nT) {
    xg_gemm<<<dim3((nT * B_) / 64), dim3(256), 0, stream>>>(
        x + (size_t)t0 * B_ * I_, W_ih, b_ih, b_hh, xgbuf);
    lstm_scan<<<dim3(B_), dim3(128), 0, stream>>>(
        xgbuf, W_hh, W_out, b_out, y, hc, t0, nT);
  }
}